// Round 1
// baseline (382.532 us; speedup 1.0000x reference)
//
#include <hip/hip_runtime.h>

#define NN 100000
#define NE 600000
#define F  128
#define BN_EPS 1e-5f

// ---------------- ws layout (byte offsets, all 128B-aligned) ----------------
// aggx   : 0          NN*F*4 = 51,200,000   (later reused as r = relu(agg@W+b))
// cnt    : 51200000   (NN+1)*4
// dinv   : 51600128   NN*4
// off    : 52000256   (NN+1)*4
// cur    : 52400384   NN*4
// csr    : 52800512   NE*4
// bsum   : 55200512   391*4
// bbase  : 55203840 - wait, computed below
// (see kernel_launch for exact offsets; total ~55.3 MB)

// ---- detect int64 vs int32 edge_index ----
__global__ void k_detect(const unsigned* __restrict__ ei, int* __restrict__ flag)
{
    __shared__ int any;
    if (threadIdx.x == 0) any = 0;
    __syncthreads();
    unsigned v = ei[2 * threadIdx.x + 1];   // odd words: int64 high halves (all 0 if i64)
    if (v != 0u) atomicOr(&any, 1);
    __syncthreads();
    if (threadIdx.x == 0) *flag = (any == 0) ? 1 : 0;   // 1 => int64
}

__global__ void k_init(int* __restrict__ cnt, float* __restrict__ colsum, float* __restrict__ colsq)
{
    int i = blockIdx.x * 256 + threadIdx.x;
    if (i <= NN) cnt[i] = 0;
    if (i < F) { colsum[i] = 0.f; colsq[i] = 0.f; }
}

__global__ void k_count(const void* __restrict__ ei, const int* __restrict__ flag, int* __restrict__ cnt)
{
    int e = blockIdx.x * 256 + threadIdx.x;
    if (e >= NE) return;
    int col;
    if (*flag) col = (int)((const long long*)ei)[NE + e];
    else       col = ((const int*)ei)[NE + e];
    atomicAdd(&cnt[col], 1);
}

__global__ void k_dinv(const int* __restrict__ cnt, float* __restrict__ dinv)
{
    int i = blockIdx.x * 256 + threadIdx.x;
    if (i < NN) {
        float d = (float)(cnt[i] + 1);          // +1 self-loop
        float r = rsqrtf(d);
        r = r * (1.5f - 0.5f * d * r * r);      // Newton refine
        dinv[i] = r;
    }
}

// ---- 3-kernel exclusive scan of cnt[0..NN] -> off[], cur[] ----
__global__ void k_bsum(const int* __restrict__ cnt, int* __restrict__ bsum)
{
    __shared__ int s[256];
    int b = blockIdx.x, t = threadIdx.x;
    int i = b * 256 + t;
    s[t] = (i <= NN) ? cnt[i] : 0;
    __syncthreads();
    for (int o = 128; o > 0; o >>= 1) {
        if (t < o) s[t] += s[t + o];
        __syncthreads();
    }
    if (t == 0) bsum[b] = s[0];
}

__global__ void k_bscan(const int* __restrict__ bsum, int* __restrict__ bbase)
{
    __shared__ int s[512];
    int t = threadIdx.x;
    int v = (t < 391) ? bsum[t] : 0;
    s[t] = v;
    __syncthreads();
    for (int o = 1; o < 512; o <<= 1) {
        int tmp = (t >= o) ? s[t - o] : 0;
        __syncthreads();
        s[t] += tmp;
        __syncthreads();
    }
    if (t < 391) bbase[t] = s[t] - v;   // exclusive
}

__global__ void k_offsets(const int* __restrict__ cnt, const int* __restrict__ bbase,
                          int* __restrict__ off, int* __restrict__ cur)
{
    __shared__ int s[256];
    int b = blockIdx.x, t = threadIdx.x;
    int i = b * 256 + t;
    int v = (i <= NN) ? cnt[i] : 0;
    s[t] = v;
    __syncthreads();
    for (int o = 1; o < 256; o <<= 1) {
        int tmp = (t >= o) ? s[t - o] : 0;
        __syncthreads();
        s[t] += tmp;
        __syncthreads();
    }
    int excl = s[t] - v + bbase[b];
    if (i <= NN) {
        off[i] = excl;
        if (i < NN) cur[i] = excl;
    }
}

__global__ void k_place(const void* __restrict__ ei, const int* __restrict__ flag,
                        int* __restrict__ cur, int* __restrict__ csr)
{
    int e = blockIdx.x * 256 + threadIdx.x;
    if (e >= NE) return;
    int row, col;
    if (*flag) {
        row = (int)((const long long*)ei)[e];
        col = (int)((const long long*)ei)[NE + e];
    } else {
        row = ((const int*)ei)[e];
        col = ((const int*)ei)[NE + e];
    }
    int slot = atomicAdd(&cur[col], 1);
    csr[slot] = row;
}

// ---- pull-style aggregation: aggx[i] = dinv[i] * (x[i]*dinv[i] + sum_e x[row]*dinv[row]) ----
__global__ __launch_bounds__(256) void k_agg(const float* __restrict__ x, const float* __restrict__ dinv,
                                             const int* __restrict__ off, const int* __restrict__ csr,
                                             float* __restrict__ aggx)
{
    int g = threadIdx.x >> 5;           // 8 nodes per block
    int lane = threadIdx.x & 31;        // 32 lanes x float4 = 128 feats
    int node = blockIdx.x * 8 + g;
    if (node >= NN) return;
    float di = dinv[node];
    float4 v = ((const float4*)(x + (size_t)node * F))[lane];
    float4 acc;
    acc.x = v.x * di; acc.y = v.y * di; acc.z = v.z * di; acc.w = v.w * di;
    int e0 = off[node], e1 = off[node + 1];
    for (int e = e0; e < e1; ++e) {
        int row = csr[e];
        float s = dinv[row];
        float4 u = ((const float4*)(x + (size_t)row * F))[lane];
        acc.x = fmaf(u.x, s, acc.x);
        acc.y = fmaf(u.y, s, acc.y);
        acc.z = fmaf(u.z, s, acc.z);
        acc.w = fmaf(u.w, s, acc.w);
    }
    float4 o;
    o.x = acc.x * di; o.y = acc.y * di; o.z = acc.z * di; o.w = acc.w * di;
    ((float4*)(aggx + (size_t)node * F))[lane] = o;
}

// ---- fused double GEMM: r = relu(aggx@W + b) (in-place into aggx), res = x@Wr + br -> d_out,
//      plus per-column sum / sumsq partials for BN ----
__global__ __launch_bounds__(256, 2) void k_gemm(
    float* __restrict__ A, const float* __restrict__ X,
    const float* __restrict__ W, const float* __restrict__ Wr,
    const float* __restrict__ bias, const float* __restrict__ biasr,
    float* __restrict__ res_out, float* __restrict__ colsum, float* __restrict__ colsq)
{
    __shared__ float At[64][F];   // 32 KB
    __shared__ float Xt[64][F];   // 32 KB
    __shared__ float Wa[16][F];   // 8 KB  (chunk of W)
    __shared__ float Wb[16][F];   // 8 KB  (chunk of Wr)   total 80 KB -> 2 blocks/CU

    const int tid = threadIdx.x;
    const int tx = tid & 31;      // cols 4*tx .. 4*tx+3
    const int ty = tid >> 5;      // rows 8*ty .. 8*ty+7
    const int r0 = blockIdx.x * 64;

#pragma unroll
    for (int it = 0; it < 8; ++it) {
        int idx = tid + it * 256;       // 0..2047
        int row = idx >> 5;
        int k4 = (idx & 31) << 2;
        int gr = r0 + row;
        float4 va = make_float4(0.f, 0.f, 0.f, 0.f);
        float4 vx = va;
        if (gr < NN) {
            va = *(const float4*)(A + (size_t)gr * F + k4);
            vx = *(const float4*)(X + (size_t)gr * F + k4);
        }
        *(float4*)(&At[row][k4]) = va;
        *(float4*)(&Xt[row][k4]) = vx;
    }

    float acc1[8][4], acc2[8][4];
#pragma unroll
    for (int i = 0; i < 8; ++i)
#pragma unroll
        for (int j = 0; j < 4; ++j) { acc1[i][j] = 0.f; acc2[i][j] = 0.f; }

    for (int c = 0; c < 8; ++c) {       // 8 chunks of 16 k
        __syncthreads();
#pragma unroll
        for (int it = 0; it < 2; ++it) {
            int idx = tid + it * 256;   // 0..511
            int kr = idx >> 5;
            int kc = (idx & 31) << 2;
            *(float4*)(&Wa[kr][kc]) = *(const float4*)(W  + (c * 16 + kr) * F + kc);
            *(float4*)(&Wb[kr][kc]) = *(const float4*)(Wr + (c * 16 + kr) * F + kc);
        }
        __syncthreads();
#pragma unroll
        for (int k0 = 0; k0 < 16; k0 += 4) {
            float w1[4][4], w2[4][4];
#pragma unroll
            for (int kk = 0; kk < 4; ++kk) {
                float4 t1 = *(const float4*)(&Wa[k0 + kk][tx * 4]);
                float4 t2 = *(const float4*)(&Wb[k0 + kk][tx * 4]);
                w1[kk][0] = t1.x; w1[kk][1] = t1.y; w1[kk][2] = t1.z; w1[kk][3] = t1.w;
                w2[kk][0] = t2.x; w2[kk][1] = t2.y; w2[kk][2] = t2.z; w2[kk][3] = t2.w;
            }
#pragma unroll
            for (int i = 0; i < 8; ++i) {
                float4 a4 = *(const float4*)(&At[ty * 8 + i][c * 16 + k0]);
                float4 x4 = *(const float4*)(&Xt[ty * 8 + i][c * 16 + k0]);
                float av[4] = {a4.x, a4.y, a4.z, a4.w};
                float xv[4] = {x4.x, x4.y, x4.z, x4.w};
#pragma unroll
                for (int kk = 0; kk < 4; ++kk)
#pragma unroll
                    for (int j = 0; j < 4; ++j) {
                        acc1[i][j] = fmaf(av[kk], w1[kk][j], acc1[i][j]);
                        acc2[i][j] = fmaf(xv[kk], w2[kk][j], acc2[i][j]);
                    }
            }
        }
    }

    __syncthreads();
    // stats overlay on Wa (compute done with it)
    float* s_sum = &Wa[0][0];
    float* s_sq  = &Wa[0][0] + 128;
    if (tid < 128) { s_sum[tid] = 0.f; s_sq[tid] = 0.f; }
    __syncthreads();

    float4 bv  = *(const float4*)(bias  + tx * 4);
    float4 brv = *(const float4*)(biasr + tx * 4);
    float bb[4]  = {bv.x, bv.y, bv.z, bv.w};
    float bb2[4] = {brv.x, brv.y, brv.z, brv.w};
    float ls[4] = {0.f, 0.f, 0.f, 0.f};
    float lq[4] = {0.f, 0.f, 0.f, 0.f};
#pragma unroll
    for (int i = 0; i < 8; ++i) {
        int gr = r0 + ty * 8 + i;
        if (gr < NN) {
            float r_[4], rs[4];
#pragma unroll
            for (int j = 0; j < 4; ++j) {
                float t = acc1[i][j] + bb[j];
                float r = fmaxf(t, 0.f);
                r_[j] = r;
                ls[j] += r;
                lq[j] = fmaf(r, r, lq[j]);
                rs[j] = acc2[i][j] + bb2[j];
            }
            *(float4*)(A + (size_t)gr * F + tx * 4)      = make_float4(r_[0], r_[1], r_[2], r_[3]);
            *(float4*)(res_out + (size_t)gr * F + tx * 4) = make_float4(rs[0], rs[1], rs[2], rs[3]);
        }
    }
#pragma unroll
    for (int j = 0; j < 4; ++j) {
        atomicAdd(&s_sum[tx * 4 + j], ls[j]);
        atomicAdd(&s_sq[tx * 4 + j], lq[j]);
    }
    __syncthreads();
    if (tid < 128) {
        atomicAdd(&colsum[tid], s_sum[tid]);
        atomicAdd(&colsq[tid], s_sq[tid]);
    }
}

__global__ void k_stats(const float* __restrict__ colsum, const float* __restrict__ colsq,
                        const float* __restrict__ gamma, const float* __restrict__ beta,
                        float* __restrict__ scale, float* __restrict__ shift)
{
    int c = threadIdx.x;
    if (c < F) {
        float inv_n = 1.0f / (float)NN;
        float mean = colsum[c] * inv_n;
        float ex2  = colsq[c] * inv_n;
        float var  = fmaxf(ex2 - mean * mean, 0.f);
        float d = var + BN_EPS;
        float is = rsqrtf(d);
        is = is * (1.5f - 0.5f * d * is * is);   // Newton refine
        float sc = gamma[c] * is;
        scale[c] = sc;
        shift[c] = beta[c] - sc * mean;
    }
}

// out = r*scale[c] + shift[c] + res   (res already in d_out)
__global__ __launch_bounds__(256) void k_final(const float* __restrict__ r,
                                               const float* __restrict__ scale,
                                               const float* __restrict__ shift,
                                               float* __restrict__ out)
{
    int idx = blockIdx.x * 256 + threadIdx.x;   // float4 index, 3.2M total (exact)
    int c4 = idx & 31;
    float4 rv = ((const float4*)r)[idx];
    float4 ov = ((float4*)out)[idx];
    float4 sv = ((const float4*)scale)[c4];
    float4 hv = ((const float4*)shift)[c4];
    float4 o;
    o.x = fmaf(rv.x, sv.x, hv.x) + ov.x;
    o.y = fmaf(rv.y, sv.y, hv.y) + ov.y;
    o.z = fmaf(rv.z, sv.z, hv.z) + ov.z;
    o.w = fmaf(rv.w, sv.w, hv.w) + ov.w;
    ((float4*)out)[idx] = o;
}

extern "C" void kernel_launch(void* const* d_in, const int* in_sizes, int n_in,
                              void* d_out, int out_size, void* d_ws, size_t ws_size,
                              hipStream_t stream)
{
    (void)in_sizes; (void)n_in; (void)out_size; (void)ws_size;
    const float* x     = (const float*)d_in[0];
    const void*  ei    = d_in[1];
    const float* W     = (const float*)d_in[2];
    const float* b     = (const float*)d_in[3];
    const float* gamma = (const float*)d_in[4];
    const float* beta  = (const float*)d_in[5];
    const float* Wres  = (const float*)d_in[6];
    const float* bres  = (const float*)d_in[7];
    float* out = (float*)d_out;

    char* w = (char*)d_ws;
    float* aggx   = (float*)(w + 0);            // 51,200,000 B
    int*   cnt    = (int*)  (w + 51200000);     // 400,004 -> pad 400,128
    float* dinv   = (float*)(w + 51600128);     // 400,000 -> 400,128
    int*   off    = (int*)  (w + 52000256);     // 400,004 -> 400,128
    int*   cur    = (int*)  (w + 52400384);     // 400,000 -> 400,128
    int*   csr    = (int*)  (w + 52800512);     // 2,400,000
    int*   bsum   = (int*)  (w + 55200512);     // 1564 -> 1664
    int*   bbase  = (int*)  (w + 55202176);     // 1564 -> 1664
    float* colsum = (float*)(w + 55203840);     // 512
    float* colsq  = (float*)(w + 55204352);     // 512
    float* scale  = (float*)(w + 55204864);     // 512
    float* shift  = (float*)(w + 55205376);     // 512
    int*   flag   = (int*)  (w + 55205888);     // 4

    const int G_INIT = 392;     // covers NN+1
    const int G_E    = (NE + 255) / 256;   // 2344
    const int G_N    = 391;     // covers NN (+1 for offsets via i<=NN)
    const int G_AGG  = 12500;   // 8 nodes/block
    const int G_GEMM = (NN + 63) / 64;     // 1563
    const int G_FIN  = (NN * F / 4) / 256; // 12500 exact

    k_detect <<<1, 256, 0, stream>>>((const unsigned*)ei, flag);
    k_init   <<<G_INIT, 256, 0, stream>>>(cnt, colsum, colsq);
    k_count  <<<G_E, 256, 0, stream>>>(ei, flag, cnt);
    k_dinv   <<<G_N, 256, 0, stream>>>(cnt, dinv);
    k_bsum   <<<G_N, 256, 0, stream>>>(cnt, bsum);
    k_bscan  <<<1, 512, 0, stream>>>(bsum, bbase);
    k_offsets<<<G_N, 256, 0, stream>>>(cnt, bbase, off, cur);
    k_place  <<<G_E, 256, 0, stream>>>(ei, flag, cur, csr);
    k_agg    <<<G_AGG, 256, 0, stream>>>(x, dinv, off, csr, aggx);
    k_gemm   <<<G_GEMM, 256, 0, stream>>>(aggx, x, W, Wres, b, bres, out, colsum, colsq);
    k_stats  <<<1, 128, 0, stream>>>(colsum, colsq, gamma, beta, scale, shift);
    k_final  <<<G_FIN, 256, 0, stream>>>(aggx, scale, shift, out);
}